// Round 10
// baseline (161.842 us; speedup 1.0000x reference)
//
#include <hip/hip_runtime.h>
#include <math.h>

// Problem constants (fixed by setup_inputs)
constexpr int Bc = 256, Sc = 1024, Dc = 32, Kc = 512;
constexpr int ST = 128;                      // s-rows per main block
constexpr float LOG2E    = 1.4426950408889634f;
constexpr float LN2      = 0.6931471805599453f;
constexpr float LOG_NORM = 29.40603306051f;  // D * 0.5 * log(2*pi)

// ROUND-10: DIAGNOSTIC (REPS amplification of the R9 kernel, method validated
// in R7). R9 helped (-1.6us, best 89.6) but missed the -8us prediction; pipe
// model (LDS 7.7 / VALU 5.1 / MFMA 4.1 us) cannot explain the ~13us rep.
// This round re-measures the loop's true counters post-fix. dur_us regresses
// by design. Pre-committed reads in the session journal: conflicts <0.5M?
// VALUBusy ~45%? MfmaUtil ~30%? -> discriminates conflict-residue vs
// latency/overlap vs VALU-wall for the round-11 change.
constexpr int REPS = 8;
constexpr float FE_SCALE = 8388608.0f;           // 2^23
constexpr float FE_BIAS  = 1064992048.0f;        // 127*2^23 - 361168

typedef __attribute__((ext_vector_type(4))) float f32x4;
typedef __attribute__((ext_vector_type(2))) long longx2;

#if __has_builtin(__builtin_amdgcn_exp2f)
#define EXP2F(v) __builtin_amdgcn_exp2f(v)
#else
#define EXP2F(v) exp2f(v)
#endif
#if __has_builtin(__builtin_amdgcn_logf)
#define LOG2F(v) __builtin_amdgcn_logf(v)
#else
#define LOG2F(v) log2f(v)
#endif

// pack 2 f32 -> 2 e4m3 bytes; word_sel is a template constant.
template <bool HI>
__device__ __forceinline__ int pkfp8(float a, float b, int old) {
    return __builtin_amdgcn_cvt_pk_fp8_f32(a, b, old, HI);
}

// ---------------- tiny prep: means -> e4m3 + m2buf[512] ----------------
__global__ __launch_bounds__(256)
void gm_m2f8(const float* __restrict__ means,
             unsigned short* __restrict__ mf8, float* __restrict__ m2buf)
{
    const int t  = blockIdx.x * 256 + threadIdx.x;   // 0..8191 (pairs)
    const float v0 = means[2 * t];
    const float v1 = means[2 * t + 1];
    mf8[t] = (unsigned short)(pkfp8<false>(v0, v1, 0) & 0xffff);
    float sq = v0 * v0 + v1 * v1;
    #pragma unroll
    for (int off = 1; off <= 8; off <<= 1) sq += __shfl_xor(sq, off);
    if ((threadIdx.x & 15) == 0) m2buf[t >> 4] = sq;   // 16 pair-threads per row
}

// ---------------- main kernel (x8-amplified hot loop, correct output) ------
__global__ __launch_bounds__(512, 4)
void gm_main(const float* __restrict__ x, const float* __restrict__ logits,
             const float* __restrict__ m2buf, const unsigned short* __restrict__ mf8,
             float* __restrict__ out)
{
    __shared__ __align__(16) unsigned char mldsT[Kc * 32]; // 16 KB fp8 means, kt-major
    __shared__ float wT[16 * 44];             // 2.75 KB fast-exp weight biases Wk
    __shared__ float x2p[ST];                 // 0.5 KB per-row sum(x^2)
    __shared__ float red[16];                 // [0..7] max, [8..15] expsum

    const int tid  = threadIdx.x;             // 0..511
    const int lane = tid & 63;
    const int wid  = tid >> 6;                // 0..7
    const int b    = blockIdx.x >> 3;
    const int s0   = (blockIdx.x & 7) * ST;
    const int q    = lane >> 4;               // k-octet of contraction dim
    const int ln   = lane & 15;
    const int rw   = wid * 16;                // this wave's 16-row subtile

    // stage means, kt-major: logical 8B entry (ch, kt) at physical byte
    // (ch<<8) + ((kt<<3) ^ (((ch>>2)&7)<<4)); spread bits distinct per octet.
    {
        const unsigned long long* src = (const unsigned long long*)mf8;
        #pragma unroll
        for (int j = 0; j < 4; ++j) {
            const int c   = tid + j * 512;           // 0..2047
            const int ktc = c >> 6;                  // component row >> 4
            const int ch  = ((c >> 2) & 15) * 4 + (c & 3);
            *(unsigned long long*)&mldsT[(ch << 8) + ((ktc << 3) ^ (((ch >> 2) & 7) << 4))]
                = src[c];
        }
    }

    // fast-exp weight bias Wk = (log2(w_k) + 127)*2^23 - c  (kt-major store)
    const float l = logits[b * Kc + tid];
    wT[(tid & 15) * 44 + (tid >> 4)] =
        fmaf((l - 0.5f * m2buf[tid]) * LOG2E, FE_SCALE, FE_BIAS);

    float mx = l;
    #pragma unroll
    for (int off = 32; off >= 1; off >>= 1) mx = fmaxf(mx, __shfl_xor(mx, off));
    if (lane == 0) red[wid] = mx;

    // x A-fragment direct from global (thread owns 8 of its row's 32 floats)
    const int row = rw + ln;
    long a;
    {
        const float4* xp = (const float4*)(x + ((size_t)b * Sc + s0 + row) * Dc) + q * 2;
        float4 v0 = xp[0], v1 = xp[1];
        int2 A;
        A.x = pkfp8<false>(v0.x * LOG2E, v0.y * LOG2E, 0);
        A.x = pkfp8<true >(v0.z * LOG2E, v0.w * LOG2E, A.x);
        A.y = pkfp8<false>(v1.x * LOG2E, v1.y * LOG2E, 0);
        A.y = pkfp8<true >(v1.z * LOG2E, v1.w * LOG2E, A.y);
        a = *(const long*)&A;
        float p = v0.x*v0.x + v0.y*v0.y + v0.z*v0.z + v0.w*v0.w
                + v1.x*v1.x + v1.y*v1.y + v1.z*v1.z + v1.w*v1.w;
        p += __shfl_xor(p, 16); p += __shfl_xor(p, 32);
        if (q == 0) x2p[row] = p;
    }
    __syncthreads();

    // finish lse start (max across the 8 waves parked in red[0..7])
    const float mxb = fmaxf(fmaxf(fmaxf(red[0], red[1]), fmaxf(red[2], red[3])),
                            fmaxf(fmaxf(red[4], red[5]), fmaxf(red[6], red[7])));
    float sm = EXP2F((l - mxb) * LOG2E);
    #pragma unroll
    for (int off = 32; off >= 1; off >>= 1) sm += __shfl_xor(sm, off);
    if (lane == 0) red[8 + wid] = sm;

    // hot loop, REPS-amplified; per-rep numerics identical to R9 (last rep
    // feeds the epilogue). Opaque z defeats hoisting; asm sink defeats DCE.
    const int ch   = ln * 4 + q;              // this thread's B-octet stream
    const int bbT  = ch << 8;
    const int swzv = (ln & 7) << 4;           // conflict-free spread bits
    const int ln44 = ln * 44;
    const f32x4 zero = {0.f, 0.f, 0.f, 0.f};
    float acc[4];

    #pragma unroll 1
    for (int rep = 0; rep < REPS; ++rep) {
        int z = 0;
        asm volatile("" : "+v"(z));           // opaque 0
        const int bbT_r  = bbT + z;
        const int ln44_r = ln44 + z;
        acc[0] = acc[1] = acc[2] = acc[3] = 0.f;
        #pragma unroll 2
        for (int kt = 0; kt < 32; kt += 4) {
            const longx2 p01 = *(const longx2*)&mldsT[bbT_r + (((kt    ) << 3) ^ swzv)];
            const longx2 p23 = *(const longx2*)&mldsT[bbT_r + (((kt + 2) << 3) ^ swzv)];
            const float4 wv4 = *(const float4*)&wT[ln44_r + kt];
            f32x4 d;
            d = __builtin_amdgcn_mfma_f32_16x16x32_fp8_fp8(a, p01.x, zero, 0, 0, 0);
            #pragma unroll
            for (int r = 0; r < 4; ++r)
                acc[r] += __int_as_float((int)fmaf(d[r], FE_SCALE, wv4.x));
            d = __builtin_amdgcn_mfma_f32_16x16x32_fp8_fp8(a, p01.y, zero, 0, 0, 0);
            #pragma unroll
            for (int r = 0; r < 4; ++r)
                acc[r] += __int_as_float((int)fmaf(d[r], FE_SCALE, wv4.y));
            d = __builtin_amdgcn_mfma_f32_16x16x32_fp8_fp8(a, p23.x, zero, 0, 0, 0);
            #pragma unroll
            for (int r = 0; r < 4; ++r)
                acc[r] += __int_as_float((int)fmaf(d[r], FE_SCALE, wv4.z));
            d = __builtin_amdgcn_mfma_f32_16x16x32_fp8_fp8(a, p23.y, zero, 0, 0, 0);
            #pragma unroll
            for (int r = 0; r < 4; ++r)
                acc[r] += __int_as_float((int)fmaf(d[r], FE_SCALE, wv4.w));
        }
        // keep this rep's results live (DCE fence, guide rule #17)
        asm volatile("" :: "v"(acc[0]), "v"(acc[1]), "v"(acc[2]), "v"(acc[3]));
    }
    __syncthreads();                          // red[8..15] ready
    const float lse  = mxb + LN2 * LOG2F(((red[8]  + red[9])  + (red[10] + red[11]))
                                       + ((red[12] + red[13]) + (red[14] + red[15])));
    const float base = LOG_NORM + lse;

    // reduce over the 16 k-columns (low-4 lane bits), then write
    #pragma unroll
    for (int r = 0; r < 4; ++r) {
        float s = acc[r];
        s += __shfl_xor(s, 1); s += __shfl_xor(s, 2);
        s += __shfl_xor(s, 4); s += __shfl_xor(s, 8);
        if (ln == 0) {
            const int r0 = rw + q * 4 + r;       // C/D row = quad*4 + reg
            out[(size_t)b * Sc + s0 + r0] = 0.5f * x2p[r0] + base - LN2 * LOG2F(s);
        }
    }
}

extern "C" void kernel_launch(void* const* d_in, const int* in_sizes, int n_in,
                              void* d_out, int out_size, void* d_ws, size_t ws_size,
                              hipStream_t stream) {
    const float* x      = (const float*)d_in[0];
    const float* logits = (const float*)d_in[1];
    const float* means  = (const float*)d_in[2];
    float* out = (float*)d_out;
    (void)in_sizes; (void)n_in; (void)out_size; (void)ws_size;

    unsigned short* mf8   = (unsigned short*)d_ws;             // 16 KB (8192 u16)
    float*          m2buf = (float*)((char*)d_ws + 16384);     //  2 KB

    hipLaunchKernelGGL(gm_m2f8, dim3(32), dim3(256), 0, stream, means, mf8, m2buf);
    hipLaunchKernelGGL(gm_main, dim3(Bc * (Sc / ST)), dim3(512), 0, stream,
                       x, logits, m2buf, mf8, out);
}

// Round 11
// 92.750 us; speedup vs baseline: 1.7449x; 1.7449x over previous
//
#include <hip/hip_runtime.h>
#include <math.h>

// Problem constants (fixed by setup_inputs)
constexpr int Bc = 256, Sc = 1024, Dc = 32, Kc = 512;
constexpr int ST = 256;                      // s-rows per block (32x32-MFMA path)
constexpr float LOG2E    = 1.4426950408889634f;
constexpr float LN2      = 0.6931471805599453f;
constexpr float LOG_NORM = 29.40603306051f;  // D * 0.5 * log(2*pi)

// ROUND-11: 16x16x32 -> 32x32x16 MFMA. R10 amplified profile: LDS pipe ~87%
// busy (incl. 17.6M conflict-cy), VALU 70% — co-limited; per-wave B-reads
// were the whole 16KB means tile per 16 output rows. 32x32 waves compute 32
// rows per tile pass -> LDS bytes/output HALVED; read pattern volume-uniform
// (stride 32B, all banks even); weights read as clean b32 broadcast.
// K=32 via two chained MFMAs (C-operand carry). Fast-exp (R8, verified) kept.
constexpr float FE_SCALE = 8388608.0f;           // 2^23
constexpr float FE_BIAS  = 1064992048.0f;        // 127*2^23 - 361168

typedef __attribute__((ext_vector_type(4)))  float f32x4;
typedef __attribute__((ext_vector_type(16))) float f32x16;
typedef __attribute__((ext_vector_type(2)))  long  longx2;

#if __has_builtin(__builtin_amdgcn_exp2f)
#define EXP2F(v) __builtin_amdgcn_exp2f(v)
#else
#define EXP2F(v) exp2f(v)
#endif
#if __has_builtin(__builtin_amdgcn_logf)
#define LOG2F(v) __builtin_amdgcn_logf(v)
#else
#define LOG2F(v) log2f(v)
#endif

// pack 2 f32 -> 2 e4m3 bytes; word_sel is a template constant.
template <bool HI>
__device__ __forceinline__ int pkfp8(float a, float b, int old) {
    return __builtin_amdgcn_cvt_pk_fp8_f32(a, b, old, HI);
}

// ---------------- tiny prep: means -> e4m3 + m2buf[512] ----------------
// Workspace poison-fill is UNCONDITIONAL (round-2 evidence) -> d_ws is free.
__global__ __launch_bounds__(256)
void gm_m2f8(const float* __restrict__ means,
             unsigned short* __restrict__ mf8, float* __restrict__ m2buf)
{
    const int t  = blockIdx.x * 256 + threadIdx.x;   // 0..8191 (pairs)
    const float v0 = means[2 * t];
    const float v1 = means[2 * t + 1];
    mf8[t] = (unsigned short)(pkfp8<false>(v0, v1, 0) & 0xffff);
    float sq = v0 * v0 + v1 * v1;
    #pragma unroll
    for (int off = 1; off <= 8; off <<= 1) sq += __shfl_xor(sq, off);
    if ((threadIdx.x & 15) == 0) m2buf[t >> 4] = sq;   // 16 pair-threads per row
}

// ---------------- main kernel ----------------
// grid(1024), 512 threads = 8 waves; wave owns 32 s-rows (ST=256/block).
// MFMA 32x32x16 fp8: A row = lane&31, K-octet = lane>>5 (call0) / +2 (call1);
// B col = lane&31, same K split; C col=lane&31, row=(r&3)+8*(r>>2)+4*(lane>>5)
// (HW-verified layout, m74/m101; dtype-independent m121-128).
//   acc = sum_k w_k * 2^(x.mu_k*log2e)  via Schraudolph fast-exp2 (R8)
//   nll = 0.5*x^2 + LOG_NORM + lse - ln2*log2(acc)
__global__ __launch_bounds__(512, 4)
void gm_main(const float* __restrict__ x, const float* __restrict__ logits,
             const float* __restrict__ m2buf, const unsigned short* __restrict__ mf8,
             float* __restrict__ out)
{
    // per component k: 32B = octets [0, 2, 1, 3] of means row k, so one b128
    // at k*32 + hi*16 yields {call0-frag, call1-frag} for that lane half.
    __shared__ __align__(16) unsigned char mlds[Kc * 32];  // 16 KB
    __shared__ float wlds[Kc];                //  2 KB fast-exp biases Wk
    __shared__ float x2p[ST];                 //  1 KB per-row sum(x^2)
    __shared__ float red[16];                 // [0..7] max, [8..15] expsum

    const int tid  = threadIdx.x;             // 0..511
    const int lane = tid & 63;
    const int wid  = tid >> 6;                // 0..7
    const int b    = blockIdx.x >> 2;
    const int s0   = (blockIdx.x & 3) * ST;
    const int l5   = lane & 31;               // MFMA row (A) and col (B/C)
    const int hi   = lane >> 5;               // K-half selector
    const int rw   = wid * 32;                // this wave's 32-row subtile

    // stage means: chunk c = (k, octet o); dest = k*32 + perm(o), perm=[0,16,8,24]
    {
        const unsigned long long* src = (const unsigned long long*)mf8;
        #pragma unroll
        for (int j = 0; j < 4; ++j) {
            const int c = tid + j * 512;       // 0..2047
            const int k = c >> 2, o = c & 3;
            *(unsigned long long*)&mlds[k * 32 + ((o & 1) << 4) + ((o & 2) << 2)]
                = src[c];
        }
    }

    // fast-exp weight bias Wk = (log2(w_k) + 127)*2^23 - c
    const float l = logits[b * Kc + tid];
    wlds[tid] = fmaf((l - 0.5f * m2buf[tid]) * LOG2E, FE_SCALE, FE_BIAS);

    float mx = l;
    #pragma unroll
    for (int off = 32; off >= 1; off >>= 1) mx = fmaxf(mx, __shfl_xor(mx, off));
    if (lane == 0) red[wid] = mx;

    // A fragments: thread owns row (s0+rw+l5), octets {hi, hi+2} (16 floats)
    long a0, a1;
    {
        const float4* xp = (const float4*)(x + ((size_t)b * Sc + s0 + rw + l5) * Dc);
        const float4 v0 = xp[2 * hi],     v1 = xp[2 * hi + 1];
        const float4 u0 = xp[2 * hi + 4], u1 = xp[2 * hi + 5];
        int2 A;
        A.x = pkfp8<false>(v0.x * LOG2E, v0.y * LOG2E, 0);
        A.x = pkfp8<true >(v0.z * LOG2E, v0.w * LOG2E, A.x);
        A.y = pkfp8<false>(v1.x * LOG2E, v1.y * LOG2E, 0);
        A.y = pkfp8<true >(v1.z * LOG2E, v1.w * LOG2E, A.y);
        a0 = *(const long*)&A;
        A.x = pkfp8<false>(u0.x * LOG2E, u0.y * LOG2E, 0);
        A.x = pkfp8<true >(u0.z * LOG2E, u0.w * LOG2E, A.x);
        A.y = pkfp8<false>(u1.x * LOG2E, u1.y * LOG2E, 0);
        A.y = pkfp8<true >(u1.z * LOG2E, u1.w * LOG2E, A.y);
        a1 = *(const long*)&A;
        float p = v0.x*v0.x + v0.y*v0.y + v0.z*v0.z + v0.w*v0.w
                + v1.x*v1.x + v1.y*v1.y + v1.z*v1.z + v1.w*v1.w
                + u0.x*u0.x + u0.y*u0.y + u0.z*u0.z + u0.w*u0.w
                + u1.x*u1.x + u1.y*u1.y + u1.z*u1.z + u1.w*u1.w;
        p += __shfl_xor(p, 32);               // partner holds the other half
        if (hi == 0) x2p[rw + l5] = p;
    }
    __syncthreads();

    // finish lse start (max across the 8 waves parked in red[0..7])
    const float mxb = fmaxf(fmaxf(fmaxf(red[0], red[1]), fmaxf(red[2], red[3])),
                            fmaxf(fmaxf(red[4], red[5]), fmaxf(red[6], red[7])));
    float sm = EXP2F((l - mxb) * LOG2E);
    #pragma unroll
    for (int off = 32; off >= 1; off >>= 1) sm += __shfl_xor(sm, off);
    if (lane == 0) red[8 + wid] = sm;

    // hot loop: 16 col-groups; per body = 1 ds_read_b128 (both K-half B-frags)
    // + 1 b32 broadcast (Wk) + 2 chained MFMA + 16 fast-exp accumulates.
    const int bb = l5 * 32 + hi * 16;
    const f32x16 zero16 = {0.f,0.f,0.f,0.f, 0.f,0.f,0.f,0.f,
                           0.f,0.f,0.f,0.f, 0.f,0.f,0.f,0.f};
    float acc[16];
    #pragma unroll
    for (int r = 0; r < 16; ++r) acc[r] = 0.f;

    #pragma unroll 2
    for (int cg = 0; cg < 16; ++cg) {
        const longx2 bp = *(const longx2*)&mlds[cg * 1024 + bb];
        const float  wv = wlds[cg * 32 + l5];      // this thread's col bias
        f32x16 d = __builtin_amdgcn_mfma_f32_32x32x16_fp8_fp8(a0, bp.x, zero16, 0, 0, 0);
        d        = __builtin_amdgcn_mfma_f32_32x32x16_fp8_fp8(a1, bp.y, d,      0, 0, 0);
        #pragma unroll
        for (int r = 0; r < 16; ++r)
            acc[r] += __int_as_float((int)fmaf(d[r], FE_SCALE, wv));
    }
    __syncthreads();                          // red[8..15] ready
    const float lse  = mxb + LN2 * LOG2F(((red[8]  + red[9])  + (red[10] + red[11]))
                                       + ((red[12] + red[13]) + (red[14] + red[15])));
    const float base = LOG_NORM + lse;

    // reduce over 32 cols (lane bits 0..4), then write: 2 writer lanes/wave
    #pragma unroll
    for (int r = 0; r < 16; ++r) {
        float s = acc[r];
        s += __shfl_xor(s, 1);  s += __shfl_xor(s, 2);
        s += __shfl_xor(s, 4);  s += __shfl_xor(s, 8);
        s += __shfl_xor(s, 16);
        if (l5 == 0) {
            const int row = rw + (r & 3) + 8 * (r >> 2) + 4 * hi;   // C/D row map
            out[(size_t)b * Sc + s0 + row] = 0.5f * x2p[row] + base - LN2 * LOG2F(s);
        }
    }
}

extern "C" void kernel_launch(void* const* d_in, const int* in_sizes, int n_in,
                              void* d_out, int out_size, void* d_ws, size_t ws_size,
                              hipStream_t stream) {
    const float* x      = (const float*)d_in[0];
    const float* logits = (const float*)d_in[1];
    const float* means  = (const float*)d_in[2];
    float* out = (float*)d_out;
    (void)in_sizes; (void)n_in; (void)out_size; (void)ws_size;

    unsigned short* mf8   = (unsigned short*)d_ws;             // 16 KB (8192 u16)
    float*          m2buf = (float*)((char*)d_ws + 16384);     //  2 KB

    hipLaunchKernelGGL(gm_m2f8, dim3(32), dim3(256), 0, stream, means, mf8, m2buf);
    hipLaunchKernelGGL(gm_main, dim3(Bc * (Sc / ST)), dim3(512), 0, stream,
                       x, logits, m2buf, mf8, out);
}